// Round 1
// baseline (469.336 us; speedup 1.0000x reference)
//
#include <hip/hip_runtime.h>

#define AMAX_CLIP 216.0f
#define BM 128
#define BN 128
#define BK 128

typedef float f32x4 __attribute__((ext_vector_type(4)));

// ---------------------------------------------------------------- amax ----
__global__ void amax_kernel(const float* __restrict__ x, unsigned* __restrict__ out, int n4) {
  int tid = blockIdx.x * blockDim.x + threadIdx.x;
  int stride = gridDim.x * blockDim.x;
  const float4* x4 = (const float4*)x;
  float m = 0.f;
  for (int i = tid; i < n4; i += stride) {
    float4 v = x4[i];
    m = fmaxf(m, fmaxf(fmaxf(fabsf(v.x), fabsf(v.y)), fmaxf(fabsf(v.z), fabsf(v.w))));
  }
#pragma unroll
  for (int off = 32; off >= 1; off >>= 1)
    m = fmaxf(m, __shfl_down(m, off));
  if ((threadIdx.x & 63) == 0) atomicMax(out, __float_as_uint(m));
}

// ----------------------------------------------------- quantize (row-major)
__global__ void quant_rowmajor(const float* __restrict__ x, unsigned char* __restrict__ q,
                               const unsigned* __restrict__ amax_bits, int nchunks) {
  float s = AMAX_CLIP / __uint_as_float(*amax_bits);
  int tid = blockIdx.x * blockDim.x + threadIdx.x;
  int stride = gridDim.x * blockDim.x;
  const float4* x4 = (const float4*)x;
  uint2* q8 = (uint2*)q;
  for (int i = tid; i < nchunks; i += stride) {
    float4 a = x4[2 * i], b = x4[2 * i + 1];
    int w0 = __builtin_amdgcn_cvt_pk_fp8_f32(a.x * s, a.y * s, 0, false);
    w0 = __builtin_amdgcn_cvt_pk_fp8_f32(a.z * s, a.w * s, w0, true);
    int w1 = __builtin_amdgcn_cvt_pk_fp8_f32(b.x * s, b.y * s, 0, false);
    w1 = __builtin_amdgcn_cvt_pk_fp8_f32(b.z * s, b.w * s, w1, true);
    q8[i] = make_uint2((unsigned)w0, (unsigned)w1);
  }
}

// ------------------------------------- quantize + transpose (B -> Bt[N][K])
__global__ void quant_transpose(const float* __restrict__ B, unsigned char* __restrict__ qt,
                                const unsigned* __restrict__ amax_bits, int N, int K) {
  __shared__ float tile[64][65];
  float s = AMAX_CLIP / __uint_as_float(*amax_bits);
  int n0 = blockIdx.x * 64;
  int k0 = blockIdx.y * 64;
  int t = threadIdx.x;
#pragma unroll
  for (int i = 0; i < 4; ++i) {
    int idx = t + i * 256;      // float4 index 0..1023
    int r = idx >> 4;           // k-row 0..63
    int c = (idx & 15) << 2;    // n-col 0..60
    float4 v = *(const float4*)&B[(size_t)(k0 + r) * N + n0 + c];
    tile[r][c + 0] = v.x; tile[r][c + 1] = v.y;
    tile[r][c + 2] = v.z; tile[r][c + 3] = v.w;
  }
  __syncthreads();
  int n = t >> 2;               // 0..63
  int ks = (t & 3) << 4;        // 0,16,32,48
  unsigned w[4];
#pragma unroll
  for (int g = 0; g < 4; ++g) {
    float f0 = tile[ks + g * 4 + 0][n] * s;
    float f1 = tile[ks + g * 4 + 1][n] * s;
    float f2 = tile[ks + g * 4 + 2][n] * s;
    float f3 = tile[ks + g * 4 + 3][n] * s;
    int ww = __builtin_amdgcn_cvt_pk_fp8_f32(f0, f1, 0, false);
    ww = __builtin_amdgcn_cvt_pk_fp8_f32(f2, f3, ww, true);
    w[g] = (unsigned)ww;
  }
  *(uint4*)&qt[(size_t)(n0 + n) * K + k0 + ks] = make_uint4(w[0], w[1], w[2], w[3]);
}

// ------------------------------------------------------------------ GEMM --
__device__ __forceinline__ void gload_lds16(const void* g, void* l) {
  __builtin_amdgcn_global_load_lds(
      (const __attribute__((address_space(1))) unsigned int*)g,
      (__attribute__((address_space(3))) unsigned int*)l, 16, 0, 0);
}

__global__ __launch_bounds__(256) void gemm_fp8(
    const unsigned char* __restrict__ A,   // M x K fp8
    const unsigned char* __restrict__ Bt,  // N x K fp8
    float* __restrict__ C,                 // M x N fp32
    const unsigned* __restrict__ amax_bits, int M, int N, int K) {
  __shared__ unsigned char lA[BM * BK];
  __shared__ unsigned char lB[BN * BK];
  int t = threadIdx.x;
  int brow = blockIdx.y * BM;
  int bcol = blockIdx.x * BN;
  int w = t >> 6, l = t & 63;
  int wm = w >> 1, wn = w & 1;

  // staging decode: LDS byte o = t*16 + i*4096 -> row r=o>>7, stored chunk
  // cs=(o>>4)&7; logical chunk cl = cs ^ (r&7)  (pre-swizzled global source)
  int r0 = t >> 3;   // +32 per i
  int cs = t & 7;

  f32x4 acc[4][4];
#pragma unroll
  for (int mi = 0; mi < 4; ++mi)
#pragma unroll
    for (int ni = 0; ni < 4; ++ni)
      acc[mi][ni] = (f32x4){0.f, 0.f, 0.f, 0.f};

  for (int kt = 0; kt < K; kt += BK) {
#pragma unroll
    for (int i = 0; i < 4; ++i) {
      int r = r0 + i * 32;
      int cl = cs ^ (r & 7);
      gload_lds16(A + (size_t)(brow + r) * K + kt + cl * 16, lA + t * 16 + i * 4096);
      gload_lds16(Bt + (size_t)(bcol + r) * K + kt + cl * 16, lB + t * 16 + i * 4096);
    }
    __syncthreads();   // compiler emits vmcnt(0) drain before barrier
#pragma unroll
    for (int kk = 0; kk < BK / 32; ++kk) {
      int kb = kk * 32 + ((l >> 4) << 3);   // this lane's k base (8 bytes)
      long av[4], bv[4];
#pragma unroll
      for (int mi = 0; mi < 4; ++mi) {
        int row = wm * 64 + mi * 16 + (l & 15);
        int off = row * BK + (((kb >> 4) ^ (row & 7)) << 4) + (kb & 15);
        av[mi] = *(const long*)(lA + off);
      }
#pragma unroll
      for (int ni = 0; ni < 4; ++ni) {
        int row = wn * 64 + ni * 16 + (l & 15);
        int off = row * BK + (((kb >> 4) ^ (row & 7)) << 4) + (kb & 15);
        bv[ni] = *(const long*)(lB + off);
      }
#pragma unroll
      for (int mi = 0; mi < 4; ++mi)
#pragma unroll
        for (int ni = 0; ni < 4; ++ni)
          acc[mi][ni] = __builtin_amdgcn_mfma_f32_16x16x32_fp8_fp8(
              av[mi], bv[ni], acc[mi][ni], 0, 0, 0);
    }
    __syncthreads();
  }

  // dequant factor, matching reference fp32 op order:
  // scale = 216/amax; scale_inv = 1/scale; out *= s1_inv*s2_inv
  float s1 = AMAX_CLIP / __uint_as_float(amax_bits[0]);
  float s2 = AMAX_CLIP / __uint_as_float(amax_bits[1]);
  float factor = (1.0f / s1) * (1.0f / s2);
  int ccol = bcol + wn * 64 + (l & 15);
  int crow0 = brow + wm * 64 + ((l >> 4) << 2);
#pragma unroll
  for (int mi = 0; mi < 4; ++mi)
#pragma unroll
    for (int ni = 0; ni < 4; ++ni)
#pragma unroll
      for (int rr = 0; rr < 4; ++rr)
        C[(size_t)(crow0 + mi * 16 + rr) * N + ccol + ni * 16] =
            acc[mi][ni][rr] * factor;
}

// ---------------------------------------------------------------- launch --
extern "C" void kernel_launch(void* const* d_in, const int* in_sizes, int n_in,
                              void* d_out, int out_size, void* d_ws, size_t ws_size,
                              hipStream_t stream) {
  const float* in1 = (const float*)d_in[0];
  const float* in2 = (const float*)d_in[1];
  float* out = (float*)d_out;
  const int M = 4096, N = 4096, K = 4096;

  unsigned char* q1 = (unsigned char*)d_ws;                 // 16 MiB
  unsigned char* q2t = q1 + (size_t)M * K;                  // 16 MiB
  unsigned* amax = (unsigned*)(q2t + (size_t)N * K);        // 2 x u32

  hipMemsetAsync(amax, 0, 2 * sizeof(unsigned), stream);
  amax_kernel<<<2048, 256, 0, stream>>>(in1, amax + 0, (M * K) >> 2);
  amax_kernel<<<2048, 256, 0, stream>>>(in2, amax + 1, (K * N) >> 2);
  quant_rowmajor<<<2048, 256, 0, stream>>>(in1, q1, amax + 0, (M * K) / 8);
  quant_transpose<<<dim3(N / 64, K / 64), 256, 0, stream>>>(in2, q2t, amax + 1, N, K);
  gemm_fp8<<<dim3(N / BN, M / BM), 256, 0, stream>>>(q1, q2t, out, amax, M, N, K);
}

// Round 4
// 295.115 us; speedup vs baseline: 1.5904x; 1.5904x over previous
//
#include <hip/hip_runtime.h>

#define AMAX_CLIP 216.0f
#define BM 128
#define BN 128
#define BK 128

typedef float f32x4 __attribute__((ext_vector_type(4)));

// ------------------------------------------------- amax partials (no atomics)
__global__ void amax_partial(const float* __restrict__ a, const float* __restrict__ b,
                             float* __restrict__ partials, int n4each, int blocksPer) {
  int half = blockIdx.x >= blocksPer;
  const float4* src = (const float4*)(half ? b : a);
  int lb = blockIdx.x - half * blocksPer;
  int tid = lb * blockDim.x + threadIdx.x;
  int stride = blocksPer * blockDim.x;
  float m = 0.f;
  for (int i = tid; i < n4each; i += stride) {
    float4 v = src[i];
    m = fmaxf(m, fmaxf(fmaxf(fabsf(v.x), fabsf(v.y)), fmaxf(fabsf(v.z), fabsf(v.w))));
  }
#pragma unroll
  for (int off = 32; off >= 1; off >>= 1) m = fmaxf(m, __shfl_down(m, off));
  __shared__ float sm[4];
  if ((threadIdx.x & 63) == 0) sm[threadIdx.x >> 6] = m;
  __syncthreads();
  if (threadIdx.x == 0)
    partials[blockIdx.x] = fmaxf(fmaxf(sm[0], sm[1]), fmaxf(sm[2], sm[3]));
}

// --------------------------------------- final reduce -> scales[2] (1 block)
__global__ void amax_finalize(const float* __restrict__ partials,
                              float* __restrict__ scales, int nPer) {
  int half = threadIdx.x >> 7;   // threads 0-127 -> input1, 128-255 -> input2
  int lt = threadIdx.x & 127;
  float m = 0.f;
  for (int i = lt; i < nPer; i += 128) m = fmaxf(m, partials[half * nPer + i]);
#pragma unroll
  for (int off = 32; off >= 1; off >>= 1) m = fmaxf(m, __shfl_down(m, off));
  __shared__ float sm[4];
  if ((threadIdx.x & 63) == 0) sm[threadIdx.x >> 6] = m;
  __syncthreads();
  // scale = amax_clip / max(|x|)  (reference fp32 op order)
  if (threadIdx.x == 0)   scales[0] = AMAX_CLIP / fmaxf(sm[0], sm[1]);
  if (threadIdx.x == 128) scales[1] = AMAX_CLIP / fmaxf(sm[2], sm[3]);
}

// ----------------------------------------------------- quantize (row-major)
__global__ void quant_rowmajor(const float* __restrict__ x, unsigned char* __restrict__ q,
                               const float* __restrict__ scale, int nchunks) {
  float s = *scale;
  int tid = blockIdx.x * blockDim.x + threadIdx.x;
  int stride = gridDim.x * blockDim.x;
  const float4* x4 = (const float4*)x;
  uint2* q8 = (uint2*)q;
  for (int i = tid; i < nchunks; i += stride) {
    float4 a = x4[2 * i], b = x4[2 * i + 1];
    int w0 = __builtin_amdgcn_cvt_pk_fp8_f32(a.x * s, a.y * s, 0, false);
    w0 = __builtin_amdgcn_cvt_pk_fp8_f32(a.z * s, a.w * s, w0, true);
    int w1 = __builtin_amdgcn_cvt_pk_fp8_f32(b.x * s, b.y * s, 0, false);
    w1 = __builtin_amdgcn_cvt_pk_fp8_f32(b.z * s, b.w * s, w1, true);
    q8[i] = make_uint2((unsigned)w0, (unsigned)w1);
  }
}

// ------------------------------------- quantize + transpose (B -> Bt[N][K])
__global__ void quant_transpose(const float* __restrict__ B, unsigned char* __restrict__ qt,
                                const float* __restrict__ scale, int N, int K) {
  __shared__ float tile[64][65];
  float s = *scale;
  int n0 = blockIdx.x * 64;
  int k0 = blockIdx.y * 64;
  int t = threadIdx.x;
#pragma unroll
  for (int i = 0; i < 4; ++i) {
    int idx = t + i * 256;      // float4 index 0..1023
    int r = idx >> 4;           // k-row 0..63
    int c = (idx & 15) << 2;    // n-col 0..60
    float4 v = *(const float4*)&B[(size_t)(k0 + r) * N + n0 + c];
    tile[r][c + 0] = v.x; tile[r][c + 1] = v.y;
    tile[r][c + 2] = v.z; tile[r][c + 3] = v.w;
  }
  __syncthreads();
  int n = t >> 2;               // 0..63
  int ks = (t & 3) << 4;        // 0,16,32,48
  unsigned w[4];
#pragma unroll
  for (int g = 0; g < 4; ++g) {
    float f0 = tile[ks + g * 4 + 0][n] * s;
    float f1 = tile[ks + g * 4 + 1][n] * s;
    float f2 = tile[ks + g * 4 + 2][n] * s;
    float f3 = tile[ks + g * 4 + 3][n] * s;
    int ww = __builtin_amdgcn_cvt_pk_fp8_f32(f0, f1, 0, false);
    ww = __builtin_amdgcn_cvt_pk_fp8_f32(f2, f3, ww, true);
    w[g] = (unsigned)ww;
  }
  *(uint4*)&qt[(size_t)(n0 + n) * K + k0 + ks] = make_uint4(w[0], w[1], w[2], w[3]);
}

// ------------------------------------------------------------------ GEMM --
__device__ __forceinline__ void gload_lds16(const void* g, void* l) {
  __builtin_amdgcn_global_load_lds(
      (const __attribute__((address_space(1))) unsigned int*)g,
      (__attribute__((address_space(3))) unsigned int*)l, 16, 0, 0);
}

__global__ __launch_bounds__(256) void gemm_fp8(
    const unsigned char* __restrict__ A,   // M x K fp8
    const unsigned char* __restrict__ Bt,  // N x K fp8
    float* __restrict__ C,                 // M x N fp32
    const float* __restrict__ scales, int M, int N, int K) {
  __shared__ unsigned char lA[BM * BK];
  __shared__ unsigned char lB[BN * BK];
  int t = threadIdx.x;
  int brow = blockIdx.y * BM;
  int bcol = blockIdx.x * BN;
  int w = t >> 6, l = t & 63;
  int wm = w >> 1, wn = w & 1;

  // staging decode: LDS byte o = t*16 + i*4096 -> row r=o>>7, stored chunk
  // cs=(o>>4)&7; logical chunk cl = cs ^ (r&7)  (pre-swizzled global source)
  int r0 = t >> 3;   // +32 per i
  int cs = t & 7;

  f32x4 acc[4][4];
#pragma unroll
  for (int mi = 0; mi < 4; ++mi)
#pragma unroll
    for (int ni = 0; ni < 4; ++ni)
      acc[mi][ni] = (f32x4){0.f, 0.f, 0.f, 0.f};

  for (int kt = 0; kt < K; kt += BK) {
#pragma unroll
    for (int i = 0; i < 4; ++i) {
      int r = r0 + i * 32;
      int cl = cs ^ (r & 7);
      gload_lds16(A + (size_t)(brow + r) * K + kt + cl * 16, lA + t * 16 + i * 4096);
      gload_lds16(Bt + (size_t)(bcol + r) * K + kt + cl * 16, lB + t * 16 + i * 4096);
    }
    __syncthreads();   // compiler emits vmcnt(0) drain before barrier
#pragma unroll
    for (int kk = 0; kk < BK / 32; ++kk) {
      int kb = kk * 32 + ((l >> 4) << 3);   // this lane's k base (8 bytes)
      long av[4], bv[4];
#pragma unroll
      for (int mi = 0; mi < 4; ++mi) {
        int row = wm * 64 + mi * 16 + (l & 15);
        int off = row * BK + (((kb >> 4) ^ (row & 7)) << 4) + (kb & 15);
        av[mi] = *(const long*)(lA + off);
      }
#pragma unroll
      for (int ni = 0; ni < 4; ++ni) {
        int row = wn * 64 + ni * 16 + (l & 15);
        int off = row * BK + (((kb >> 4) ^ (row & 7)) << 4) + (kb & 15);
        bv[ni] = *(const long*)(lB + off);
      }
#pragma unroll
      for (int mi = 0; mi < 4; ++mi)
#pragma unroll
        for (int ni = 0; ni < 4; ++ni)
          acc[mi][ni] = __builtin_amdgcn_mfma_f32_16x16x32_fp8_fp8(
              av[mi], bv[ni], acc[mi][ni], 0, 0, 0);
    }
    __syncthreads();
  }

  // dequant factor, matching reference fp32 op order:
  // scale = 216/amax; scale_inv = 1/scale; out *= s1_inv*s2_inv
  float s1 = scales[0];
  float s2 = scales[1];
  float factor = (1.0f / s1) * (1.0f / s2);
  int ccol = bcol + wn * 64 + (l & 15);
  int crow0 = brow + wm * 64 + ((l >> 4) << 2);
#pragma unroll
  for (int mi = 0; mi < 4; ++mi)
#pragma unroll
    for (int ni = 0; ni < 4; ++ni)
#pragma unroll
      for (int rr = 0; rr < 4; ++rr)
        C[(size_t)(crow0 + mi * 16 + rr) * N + ccol + ni * 16] =
            acc[mi][ni][rr] * factor;
}

// ---------------------------------------------------------------- launch --
extern "C" void kernel_launch(void* const* d_in, const int* in_sizes, int n_in,
                              void* d_out, int out_size, void* d_ws, size_t ws_size,
                              hipStream_t stream) {
  const float* in1 = (const float*)d_in[0];
  const float* in2 = (const float*)d_in[1];
  float* out = (float*)d_out;
  const int M = 4096, N = 4096, K = 4096;

  float* scales = (float*)d_ws;                               // 2 floats @ offset 0
  unsigned char* q1 = (unsigned char*)d_ws + 256;             // 16 MiB
  unsigned char* q2t = q1 + (size_t)M * K;                    // 16 MiB
  // partials overlay the q1 region: written by amax_partial, consumed by
  // amax_finalize, then dead before quant_rowmajor overwrites q1.
  float* partials = (float*)q1;                               // 2048 floats

  const int blocksPer = 1024;
  amax_partial<<<2 * blocksPer, 256, 0, stream>>>(in1, in2, partials, (M * K) >> 2, blocksPer);
  amax_finalize<<<1, 256, 0, stream>>>(partials, scales, blocksPer);
  quant_rowmajor<<<2048, 256, 0, stream>>>(in1, q1, scales + 0, (M * K) / 8);
  quant_transpose<<<dim3(N / 64, K / 64), 256, 0, stream>>>(in2, q2t, scales + 1, N, K);
  gemm_fp8<<<dim3(N / BN, M / BM), 256, 0, stream>>>(q1, q2t, out, scales, M, N, K);
}